// Round 6
// baseline (845.628 us; speedup 1.0000x reference)
//
#include <hip/hip_runtime.h>
#include <stdint.h>

#define HH 112
#define WW 112
#define CC 512
#define BB 4
#define LLEN (HH*WW)
#define NTOK (BB*LLEN)   // 50176
#define NHEADS 8
#define HD 64
#define HIDDEN 2048

typedef __bf16 bf16x8 __attribute__((ext_vector_type(8)));
typedef float f32x4 __attribute__((ext_vector_type(4)));

__device__ __forceinline__ unsigned short f2bf(float x) {
  uint32_t u = __float_as_uint(x);
  u += 0x7fffu + ((u >> 16) & 1u);
  return (unsigned short)(u >> 16);
}
__device__ __forceinline__ float bf2f(unsigned short h) {
  return __uint_as_float((uint32_t)h << 16);
}

// async global->LDS, 16B per lane; lds dest must be wave-uniform base
__device__ __forceinline__ void gload16(const void* gptr, void* lptr) {
  __builtin_amdgcn_global_load_lds(
      (const __attribute__((address_space(1))) void*)gptr,
      (__attribute__((address_space(3))) void*)lptr,
      16, 0, 0);
}

// ---------------- weight transpose (K,N) f32 -> (N,K) bf16 ----------------
__global__ __launch_bounds__(256) void wtranspose_kernel(
    const float* __restrict__ w, unsigned short* __restrict__ wt, int K, int N) {
  int idx = blockIdx.x * 256 + threadIdx.x;
  if (idx >= K * N) return;
  int k = idx / N, n = idx - k * N;
  wt[(size_t)n * K + k] = f2bf(w[idx]);
}

// ---------------- depthwise 3x3 conv + bias + residual ----------------
__global__ __launch_bounds__(256) void cpe_kernel(
    const float* __restrict__ x, const float* __restrict__ w,
    const float* __restrict__ bias, float* __restrict__ out) {
  int tid = blockIdx.x * 256 + threadIdx.x;
  int c = (tid & 127) << 2;      // channel chunk of 4
  int pix = tid >> 7;
  int xx = pix % WW; int t2 = pix / WW; int yy = t2 % HH; int bb = t2 / HH;
  float4 bv = *(const float4*)(&bias[c]);
  float ax = bv.x, ay = bv.y, az = bv.z, aw = bv.w;
  #pragma unroll
  for (int ky = 0; ky < 3; ky++) {
    int y = yy + ky - 1;
    if ((unsigned)y >= (unsigned)HH) continue;
    #pragma unroll
    for (int kx = 0; kx < 3; kx++) {
      int x2 = xx + kx - 1;
      if ((unsigned)x2 >= (unsigned)WW) continue;
      const float4 v = *(const float4*)(&x[(((size_t)bb * HH + y) * WW + x2) * CC + c]);
      const float4 wv = *(const float4*)(&w[(ky * 3 + kx) * CC + c]);
      ax = fmaf(v.x, wv.x, ax); ay = fmaf(v.y, wv.y, ay);
      az = fmaf(v.z, wv.z, az); aw = fmaf(v.w, wv.w, aw);
    }
  }
  size_t o = (size_t)pix * CC + c;
  const float4 xv = *(const float4*)(&x[o]);
  float4 r; r.x = xv.x + ax; r.y = xv.y + ay; r.z = xv.z + az; r.w = xv.w + aw;
  *(float4*)(&out[o]) = r;
}

// ---------------- LayerNorm (C=512), one wave per token, bf16 out ----------------
__global__ __launch_bounds__(256) void ln_kernel(
    const float* __restrict__ in, const float* __restrict__ g,
    const float* __restrict__ b, unsigned short* __restrict__ out) {
  int token = (blockIdx.x * 256 + threadIdx.x) >> 6;
  int lane = threadIdx.x & 63;
  const float* row = in + (size_t)token * CC;
  float4 v0 = *(const float4*)(row + lane * 8);
  float4 v1 = *(const float4*)(row + lane * 8 + 4);
  float s = v0.x + v0.y + v0.z + v0.w + v1.x + v1.y + v1.z + v1.w;
  float ss = v0.x*v0.x + v0.y*v0.y + v0.z*v0.z + v0.w*v0.w
           + v1.x*v1.x + v1.y*v1.y + v1.z*v1.z + v1.w*v1.w;
  #pragma unroll
  for (int o = 32; o; o >>= 1) { s += __shfl_xor(s, o, 64); ss += __shfl_xor(ss, o, 64); }
  float mu = s * (1.f / CC);
  float var = ss * (1.f / CC) - mu * mu;
  float rs = rsqrtf(var + 1e-5f);
  float4 g0 = *(const float4*)(&g[lane * 8]);
  float4 g1 = *(const float4*)(&g[lane * 8 + 4]);
  float4 b0 = *(const float4*)(&b[lane * 8]);
  float4 b1 = *(const float4*)(&b[lane * 8 + 4]);
  unsigned short o8[8];
  o8[0] = f2bf((v0.x - mu) * rs * g0.x + b0.x);
  o8[1] = f2bf((v0.y - mu) * rs * g0.y + b0.y);
  o8[2] = f2bf((v0.z - mu) * rs * g0.z + b0.z);
  o8[3] = f2bf((v0.w - mu) * rs * g0.w + b0.w);
  o8[4] = f2bf((v1.x - mu) * rs * g1.x + b1.x);
  o8[5] = f2bf((v1.y - mu) * rs * g1.y + b1.y);
  o8[6] = f2bf((v1.z - mu) * rs * g1.z + b1.z);
  o8[7] = f2bf((v1.w - mu) * rs * g1.w + b1.w);
  uint4 pk;
  pk.x = (uint32_t)o8[0] | ((uint32_t)o8[1] << 16);
  pk.y = (uint32_t)o8[2] | ((uint32_t)o8[3] << 16);
  pk.z = (uint32_t)o8[4] | ((uint32_t)o8[5] << 16);
  pk.w = (uint32_t)o8[6] | ((uint32_t)o8[7] << 16);
  *(uint4*)(&out[(size_t)token * CC + lane * 8]) = pk;
}

// ======== bf16 MFMA GEMM: 8-phase schedule (T2+T3+T4+T5), 256x256xBK64 ========
// 512 thr = 8 waves (2M x 4N). Per-wave C = (rows wr*64+[0,64) U 128+wr*64+[0,64))
//                              x (cols wc*32+[0,32) U 128+wc*32+[0,32))
// so EVERY wave consumes half-tile (A,rh)/(B,ch) at the same phase.
// LDS: dbuf x {A,B} x 2 halves x (128 rows x 64 k) bf16 = 128 KB, 1 block/CU.
// Per K-tile: 4 phases (rh,ch) = (0,0),(0,1),(1,0),(1,1):
//   vmcnt(N) + barrier -> ds_read frags -> stage 1 half of t+1 -> lgkmcnt(0)
//   + sched_barrier(0) -> setprio(1) + 16 MFMA + setprio(0)
// Stage order per tile: A0@p0, B0@p1, B1@p2, A1@p3  (2 gloads each).
// vmcnt ledger (own loads, 2/half): p0: {A0..A1(t)}=8 out, need A0,B0 -> vmcnt(4)
//   p1: {B1,A1(t),A0(t+1)}=6, need B1 -> vmcnt(4);  p2: {A1(t),A0,B0(t+1)}=6,
//   need A1 -> vmcnt(4);  p3: none. Last tile (no stages): {4,2,0,-}.
// T2 swizzle both-sides (rule 21): LDS[r][c] = global[r][c ^ (r&7)] (16B chunks).
#define BM 256
#define BN 256
#define BK 64

#define WAITV(N) asm volatile("s_waitcnt vmcnt(" #N ")" ::: "memory")
#define BAR() __builtin_amdgcn_s_barrier()
#define WAITL() do { asm volatile("s_waitcnt lgkmcnt(0)" ::: "memory"); \
                     __builtin_amdgcn_sched_barrier(0); } while (0)

template <int MODE>
__global__ __launch_bounds__(512) void gemm_kernel(
    const unsigned short* __restrict__ A, const unsigned short* __restrict__ BT,
    const float* __restrict__ bias, const float* __restrict__ res,
    float* __restrict__ outF, unsigned short* __restrict__ outB,
    int M, int N, int K) {
  __shared__ unsigned short As[2][2][128 * 64];   // [buf][half][r*64+c]
  __shared__ unsigned short Bs[2][2][128 * 64];
  // XCD-aware swizzle (all grids divisible by 8)
  int nwg = gridDim.x * gridDim.y;
  int flat = blockIdx.y * gridDim.x + blockIdx.x;
  int swz = (flat & 7) * (nwg >> 3) + (flat >> 3);
  int bx = swz % gridDim.x, by = swz / gridDim.x;
  const int bm = by * BM, bn = bx * BN;
  const int t = threadIdx.x;
  const int wid = t >> 6, lane = t & 63;
  const int wr = wid >> 2, wc = wid & 3;          // 2M x 4N wave grid
  const int lr = lane & 15, g = lane >> 4;
  // staging: wave wid, q in {0,1}: rows 8*wid + 64*q + (lane>>3) of the half,
  // src chunk = (lane&7) ^ (row&7)  (row&7 == lane>>3)
  const int srow8 = lane >> 3;
  const int schunk = ((lane & 7) ^ srow8) * 8;
  const size_t aBase = (size_t)(bm + 8 * wid + srow8) * K + schunk;
  const size_t bBase = (size_t)(bn + 8 * wid + srow8) * K + schunk;
  const size_t rowK64  = (size_t)64 * K;
  const size_t rowK128 = (size_t)128 * K;
  const int ldst = wid * 512;                     // elems; lane*16B auto-added

#define STAGE_A(BUF, HALF, KT) do { \
    const unsigned short* s_ = A + aBase + (size_t)(HALF) * rowK128 + (KT); \
    gload16(s_,          &As[BUF][HALF][ldst]); \
    gload16(s_ + rowK64, &As[BUF][HALF][4096 + ldst]); } while (0)
#define STAGE_B(BUF, HALF, KT) do { \
    const unsigned short* s_ = BT + bBase + (size_t)(HALF) * rowK128 + (KT); \
    gload16(s_,          &Bs[BUF][HALF][ldst]); \
    gload16(s_ + rowK64, &Bs[BUF][HALF][4096 + ldst]); } while (0)

  // read-side swizzle: ks chunk (4ks+g) ^ (lr&7)
  const int rchunk0 = ((g)     ^ (lr & 7)) * 8;
  const int rchunk1 = ((g + 4) ^ (lr & 7)) * 8;
  const int arow_off = (wr * 64 + lr) * 64;
  const int brow_off = (wc * 32 + lr) * 64;

#define LOAD_A(BUF, RH) do { \
    const unsigned short* h_ = &As[BUF][RH][0]; \
    _Pragma("unroll") for (int i_ = 0; i_ < 4; i_++) { \
      af[i_][0] = *(const bf16x8*)&h_[arow_off + i_ * 1024 + rchunk0]; \
      af[i_][1] = *(const bf16x8*)&h_[arow_off + i_ * 1024 + rchunk1]; } } while (0)
#define LOAD_B(BUF, CH) do { \
    const unsigned short* h_ = &Bs[BUF][CH][0]; \
    _Pragma("unroll") for (int j_ = 0; j_ < 2; j_++) { \
      bfq[j_][0] = *(const bf16x8*)&h_[brow_off + j_ * 1024 + rchunk0]; \
      bfq[j_][1] = *(const bf16x8*)&h_[brow_off + j_ * 1024 + rchunk1]; } } while (0)

#define MFMA16(RH, CH) do { \
    __builtin_amdgcn_s_setprio(1); \
    _Pragma("unroll") for (int i_ = 0; i_ < 4; i_++) \
      _Pragma("unroll") for (int j_ = 0; j_ < 2; j_++) { \
        acc[(RH)*4+i_][(CH)*2+j_] = __builtin_amdgcn_mfma_f32_16x16x32_bf16( \
            af[i_][0], bfq[j_][0], acc[(RH)*4+i_][(CH)*2+j_], 0, 0, 0); \
        acc[(RH)*4+i_][(CH)*2+j_] = __builtin_amdgcn_mfma_f32_16x16x32_bf16( \
            af[i_][1], bfq[j_][1], acc[(RH)*4+i_][(CH)*2+j_], 0, 0, 0); } \
    __builtin_amdgcn_s_setprio(0); } while (0)

  f32x4 acc[8][4] = {};
  bf16x8 af[4][2], bfq[2][2];
  const int nt = K / BK;

  // prologue: stage tile 0, queue order A0 B0 B1 A1
  STAGE_A(0, 0, 0);
  STAGE_B(0, 0, 0);
  STAGE_B(0, 1, 0);
  STAGE_A(0, 1, 0);

  for (int tt = 0; tt < nt - 1; ++tt) {
    const int buf = tt & 1, nbuf = buf ^ 1;
    const int ktn = (tt + 1) * BK;
    // phase 0 (rh0, ch0)
    WAITV(4); BAR();
    LOAD_A(buf, 0); LOAD_B(buf, 0);
    STAGE_A(nbuf, 0, ktn);
    WAITL();
    MFMA16(0, 0);
    // phase 1 (rh0, ch1)
    WAITV(4); BAR();
    LOAD_B(buf, 1);
    STAGE_B(nbuf, 0, ktn);
    WAITL();
    MFMA16(0, 1);
    // phase 2 (rh1, ch0)
    WAITV(4); BAR();
    LOAD_A(buf, 1); LOAD_B(buf, 0);
    STAGE_B(nbuf, 1, ktn);
    WAITL();
    MFMA16(1, 0);
    // phase 3 (rh1, ch1)
    BAR();
    LOAD_B(buf, 1);
    STAGE_A(nbuf, 1, ktn);
    WAITL();
    MFMA16(1, 1);
  }
  // peeled last tile: waits {4,2,0,-}, no staging
  {
    const int buf = (nt - 1) & 1;
    WAITV(4); BAR();
    LOAD_A(buf, 0); LOAD_B(buf, 0);
    WAITL();
    MFMA16(0, 0);
    WAITV(2); BAR();
    LOAD_B(buf, 1);
    WAITL();
    MFMA16(0, 1);
    WAITV(0); BAR();
    LOAD_A(buf, 1); LOAD_B(buf, 0);
    WAITL();
    MFMA16(1, 0);
    BAR();
    LOAD_B(buf, 1);
    WAITL();
    MFMA16(1, 1);
  }

  // epilogue: C row = bm + rh*128 + wr*64 + i*16 + g*4 + r ; col = bn + ch*128
  //           + wc*32 + j*16 + lr
  const int orow = g * 4, ocol = lr;
  #pragma unroll
  for (int it = 0; it < 8; it++) {
    const int rh = it >> 2, i = it & 3;
    #pragma unroll
    for (int jt = 0; jt < 4; jt++) {
      const int ch = jt >> 1, j = jt & 1;
      int gc = bn + ch * 128 + wc * 32 + j * 16 + ocol;
      float bv = bias[gc];
      #pragma unroll
      for (int r = 0; r < 4; r++) {
        int gr = bm + rh * 128 + wr * 64 + i * 16 + orow + r;
        size_t off = (size_t)gr * N + gc;
        float v = acc[it][jt][r] + bv;
        if (MODE == 0) {
          outB[off] = f2bf(v);
        } else if (MODE == 1) {
          outF[off] = v + res[off];
        } else {
          float u = 0.79788456080286536f * (v + 0.044715f * v * v * v);
          float e = __expf(2.f * u);
          float th = 1.f - 2.f / (e + 1.f);
          outB[off] = f2bf(0.5f * v * (1.f + th));
        }
      }
    }
  }
}

// ---------------- MFMA window attention: 1 wave per (window, head) ----------------
#define WNS 68   // LDS row stride (elems): 136B = 8B aligned, odd-dword for banks

__global__ __launch_bounds__(64) void attn_mfma_kernel(
    const unsigned short* __restrict__ qkv, unsigned short* __restrict__ out) {
  __shared__ unsigned short VT[64 * WNS];   // V^T: [d][k]
  __shared__ unsigned short Ps[64 * WNS];   // P:   [q][k]
  const int task = blockIdx.x;
  const int win = task >> 3, h = task & 7;
  const int b = win >> 8, wy = (win >> 4) & 15, wx = win & 15;
  const int lane = threadIdx.x;
  const int lr = lane & 15, g = lane >> 4;

  auto tokof = [&](int r) {
    int rr = r > 48 ? 48 : r;
    int y = rr / 7, x2 = rr - y * 7;
    return (size_t)(b * LLEN + (wy * 7 + y) * WW + wx * 7 + x2);
  };

  // ---- stage V^T (scalar writes: per-instruction row base uniform -> conflict-free)
  {
    size_t vbase = tokof(lane) * 1536 + h * 64 + 1024;
    bool valid = lane <= 48;
    #pragma unroll
    for (int c = 0; c < 8; c++) {
      uint4 v = *(const uint4*)(&qkv[vbase + c * 8]);
      const unsigned short* pv = (const unsigned short*)&v;
      #pragma unroll
      for (int e = 0; e < 8; e++)
        VT[(c * 8 + e) * WNS + lane] = valid ? pv[e] : (unsigned short)0;
    }
  }

  // ---- Q,K fragments straight from global (A/B frag rows = lr + 16*tile)
  size_t tok[4];
  #pragma unroll
  for (int i2 = 0; i2 < 4; i2++) tok[i2] = tokof(i2 * 16 + lr);
  bf16x8 Qf[4][2], Kf[4][2];
  #pragma unroll
  for (int i2 = 0; i2 < 4; i2++) {
    size_t base = tok[i2] * 1536 + h * 64 + g * 8;
    #pragma unroll
    for (int ks = 0; ks < 2; ks++) {
      Qf[i2][ks] = *(const bf16x8*)(&qkv[base + ks * 32]);
      Kf[i2][ks] = *(const bf16x8*)(&qkv[base + 512 + ks * 32]);
    }
  }

  // ---- S^T = K·Q^T : acc[i=k-tile][j=q-tile], C row = k, col = q
  f32x4 acc[4][4] = {};
  #pragma unroll
  for (int ks = 0; ks < 2; ks++)
    #pragma unroll
    for (int i2 = 0; i2 < 4; i2++)
      #pragma unroll
      for (int j = 0; j < 4; j++)
        acc[i2][j] = __builtin_amdgcn_mfma_f32_16x16x32_bf16(Kf[i2][ks], Qf[j][ks], acc[i2][j], 0, 0, 0);

  // ---- softmax over k (row axis of S^T): in-reg over 16 vals + shfl 16,32
  #pragma unroll
  for (int j = 0; j < 4; j++) {
    float mx = -1e30f;
    #pragma unroll
    for (int i2 = 0; i2 < 4; i2++)
      #pragma unroll
      for (int r = 0; r < 4; r++) {
        int k = 16 * i2 + 4 * g + r;
        mx = fmaxf(mx, (k <= 48) ? acc[i2][j][r] : -1e30f);
      }
    mx = fmaxf(mx, __shfl_xor(mx, 16, 64));
    mx = fmaxf(mx, __shfl_xor(mx, 32, 64));
    float p[4][4];
    float sum = 0.f;
    #pragma unroll
    for (int i2 = 0; i2 < 4; i2++)
      #pragma unroll
      for (int r = 0; r < 4; r++) {
        int k = 16 * i2 + 4 * g + r;
        float e = (k <= 48) ? __expf(0.125f * (acc[i2][j][r] - mx)) : 0.f;
        p[i2][r] = e; sum += e;
      }
    sum += __shfl_xor(sum, 16, 64);
    sum += __shfl_xor(sum, 32, 64);
    float inv = 1.f / sum;
    int q = 16 * j + lr;
    #pragma unroll
    for (int i2 = 0; i2 < 4; i2++) {
      uint2 w;
      w.x = (uint32_t)f2bf(p[i2][0] * inv) | ((uint32_t)f2bf(p[i2][1] * inv) << 16);
      w.y = (uint32_t)f2bf(p[i2][2] * inv) | ((uint32_t)f2bf(p[i2][3] * inv) << 16);
      *(uint2*)(&Ps[q * WNS + 16 * i2 + 4 * g]) = w;
    }
  }

  __syncthreads();   // VT + Ps writes -> reads fence

  // ---- O = P·V : A = P[q][k], B^T = VT[d][k]; o[i=q-tile][j=d-tile]
  f32x4 o[4][4] = {};
  #pragma unroll
  for (int ks = 0; ks < 2; ks++) {
    bf16x8 Pf[4], Vf[4];
    #pragma unroll
    for (int i2 = 0; i2 < 4; i2++) {
      int base = (16 * i2 + lr) * WNS + ks * 32 + g * 8;
      uint2 lo = *(const uint2*)(&Ps[base]);
      uint2 hi = *(const uint2*)(&Ps[base + 4]);
      uint4 u; u.x = lo.x; u.y = lo.y; u.z = hi.x; u.w = hi.y;
      Pf[i2] = *(bf16x8*)&u;
    }
    #pragma unroll
    for (int j = 0; j < 4; j++) {
      int base = (16 * j + lr) * WNS + ks * 32 + g * 8;
      uint2 lo = *(const uint2*)(&VT[base]);
      uint2 hi = *(const uint2*)(&VT[base + 4]);
      uint4 u; u.x = lo.x; u.y = lo.y; u.z = hi.x; u.w = hi.y;
      Vf[j] = *(bf16x8*)&u;
    }
    #pragma unroll
    for (int i2 = 0; i2 < 4; i2++)
      #pragma unroll
      for (int j = 0; j < 4; j++)
        o[i2][j] = __builtin_amdgcn_mfma_f32_16x16x32_bf16(Pf[i2], Vf[j], o[i2][j], 0, 0, 0);
  }

  // ---- store O rows q<49
  #pragma unroll
  for (int i2 = 0; i2 < 4; i2++)
    #pragma unroll
    for (int r = 0; r < 4; r++) {
      int q = 16 * i2 + 4 * g + r;
      if (q <= 48) {
        size_t obase = tokof(q) * 512 + h * 64 + lr;
        #pragma unroll
        for (int j = 0; j < 4; j++)
          out[obase + 16 * j] = f2bf(o[i2][j][r]);
      }
    }
}

extern "C" void kernel_launch(void* const* d_in, const int* in_sizes, int n_in,
                              void* d_out, int out_size, void* d_ws, size_t ws_size,
                              hipStream_t stream) {
  const float* x      = (const float*)d_in[0];
  const float* cpe0_w = (const float*)d_in[1];
  const float* cpe0_b = (const float*)d_in[2];
  const float* cpe1_w = (const float*)d_in[3];
  const float* cpe1_b = (const float*)d_in[4];
  const float* ln1_g  = (const float*)d_in[5];
  const float* ln1_b  = (const float*)d_in[6];
  const float* ln2_g  = (const float*)d_in[7];
  const float* ln2_b  = (const float*)d_in[8];
  const float* qkv_w  = (const float*)d_in[9];
  const float* qkv_b  = (const float*)d_in[10];
  const float* proj_w = (const float*)d_in[11];
  const float* proj_b = (const float*)d_in[12];
  const float* fc1_w  = (const float*)d_in[13];
  const float* fc1_b  = (const float*)d_in[14];
  const float* fc2_w  = (const float*)d_in[15];
  const float* fc2_b  = (const float*)d_in[16];
  float* out = (float*)d_out;
  char* ws = (char*)d_ws;

  unsigned short* qkvwT  = (unsigned short*)(ws + 0);           // 1536x512 bf16
  unsigned short* projwT = (unsigned short*)(ws + 1572864);     // 512x512
  unsigned short* fc1wT  = (unsigned short*)(ws + 2097152);     // 2048x512
  unsigned short* fc2wT  = (unsigned short*)(ws + 4194304);     // 512x2048
  float*          shortc = (float*)(ws + 6291456);              // 50176x512 f32
  unsigned short* lnb    = (unsigned short*)(ws + 109051904);   // 50176x512 bf16
  unsigned short* qkvb   = (unsigned short*)(ws + 160432128);   // 50176x1536 bf16
  unsigned short* attnb  = (unsigned short*)(ws + 314572800);   // 50176x512 bf16
  unsigned short* gelub  = qkvb;   // overlay: 50176x2048 bf16
  float* h2 = out;                 // reuse d_out as h2 scratch

  wtranspose_kernel<<<(512 * 1536 + 255) / 256, 256, 0, stream>>>(qkv_w, qkvwT, 512, 1536);
  wtranspose_kernel<<<(512 * 512 + 255) / 256, 256, 0, stream>>>(proj_w, projwT, 512, 512);
  wtranspose_kernel<<<(512 * 2048 + 255) / 256, 256, 0, stream>>>(fc1_w, fc1wT, 512, 2048);
  wtranspose_kernel<<<(2048 * 512 + 255) / 256, 256, 0, stream>>>(fc2_w, fc2wT, 2048, 512);

  const int pixblocks = (BB * HH * WW * 128) / 256;   // 25088
  cpe_kernel<<<pixblocks, 256, 0, stream>>>(x, cpe0_w, cpe0_b, shortc);
  ln_kernel<<<NTOK / 4, 256, 0, stream>>>(shortc, ln1_g, ln1_b, lnb);
  gemm_kernel<0><<<dim3(6, 196), 512, 0, stream>>>(lnb, qkvwT, qkv_b, nullptr,
                                                   nullptr, qkvb, NTOK, 1536, 512);
  attn_mfma_kernel<<<8192, 64, 0, stream>>>(qkvb, attnb);
  gemm_kernel<1><<<dim3(2, 196), 512, 0, stream>>>(attnb, projwT, proj_b, shortc,
                                                   shortc, nullptr, NTOK, 512, 512);
  cpe_kernel<<<pixblocks, 256, 0, stream>>>(shortc, cpe1_w, cpe1_b, h2);
  ln_kernel<<<NTOK / 4, 256, 0, stream>>>(h2, ln2_g, ln2_b, lnb);
  gemm_kernel<2><<<dim3(8, 196), 512, 0, stream>>>(lnb, fc1wT, fc1_b, nullptr,
                                                   nullptr, gelub, NTOK, 2048, 512);
  gemm_kernel<1><<<dim3(2, 196), 512, 0, stream>>>(gelub, fc2wT, fc2_b, h2,
                                                   out, nullptr, NTOK, 512, 2048);
}

// Round 7
// 791.455 us; speedup vs baseline: 1.0684x; 1.0684x over previous
//
#include <hip/hip_runtime.h>
#include <stdint.h>

#define HH 112
#define WW 112
#define CC 512
#define BB 4
#define LLEN (HH*WW)
#define NTOK (BB*LLEN)   // 50176
#define NHEADS 8
#define HD 64
#define HIDDEN 2048

typedef __bf16 bf16x8 __attribute__((ext_vector_type(8)));
typedef float f32x4 __attribute__((ext_vector_type(4)));

__device__ __forceinline__ unsigned short f2bf(float x) {
  uint32_t u = __float_as_uint(x);
  u += 0x7fffu + ((u >> 16) & 1u);
  return (unsigned short)(u >> 16);
}
__device__ __forceinline__ float bf2f(unsigned short h) {
  return __uint_as_float((uint32_t)h << 16);
}

// async global->LDS, 16B per lane; lds dest must be wave-uniform base
__device__ __forceinline__ void gload16(const void* gptr, void* lptr) {
  __builtin_amdgcn_global_load_lds(
      (const __attribute__((address_space(1))) void*)gptr,
      (__attribute__((address_space(3))) void*)lptr,
      16, 0, 0);
}

// ---------------- weight transpose (K,N) f32 -> (N,K) bf16 ----------------
__global__ __launch_bounds__(256) void wtranspose_kernel(
    const float* __restrict__ w, unsigned short* __restrict__ wt, int K, int N) {
  int idx = blockIdx.x * 256 + threadIdx.x;
  if (idx >= K * N) return;
  int k = idx / N, n = idx - k * N;
  wt[(size_t)n * K + k] = f2bf(w[idx]);
}

// ---------------- depthwise 3x3 conv + bias + residual ----------------
__global__ __launch_bounds__(256) void cpe_kernel(
    const float* __restrict__ x, const float* __restrict__ w,
    const float* __restrict__ bias, float* __restrict__ out) {
  int tid = blockIdx.x * 256 + threadIdx.x;
  int c = (tid & 127) << 2;      // channel chunk of 4
  int pix = tid >> 7;
  int xx = pix % WW; int t2 = pix / WW; int yy = t2 % HH; int bb = t2 / HH;
  float4 bv = *(const float4*)(&bias[c]);
  float ax = bv.x, ay = bv.y, az = bv.z, aw = bv.w;
  #pragma unroll
  for (int ky = 0; ky < 3; ky++) {
    int y = yy + ky - 1;
    if ((unsigned)y >= (unsigned)HH) continue;
    #pragma unroll
    for (int kx = 0; kx < 3; kx++) {
      int x2 = xx + kx - 1;
      if ((unsigned)x2 >= (unsigned)WW) continue;
      const float4 v = *(const float4*)(&x[(((size_t)bb * HH + y) * WW + x2) * CC + c]);
      const float4 wv = *(const float4*)(&w[(ky * 3 + kx) * CC + c]);
      ax = fmaf(v.x, wv.x, ax); ay = fmaf(v.y, wv.y, ay);
      az = fmaf(v.z, wv.z, az); aw = fmaf(v.w, wv.w, aw);
    }
  }
  size_t o = (size_t)pix * CC + c;
  const float4 xv = *(const float4*)(&x[o]);
  float4 r; r.x = xv.x + ax; r.y = xv.y + ay; r.z = xv.z + az; r.w = xv.w + aw;
  *(float4*)(&out[o]) = r;
}

// ---------------- LayerNorm (C=512), one wave per token, bf16 out ----------------
__global__ __launch_bounds__(256) void ln_kernel(
    const float* __restrict__ in, const float* __restrict__ g,
    const float* __restrict__ b, unsigned short* __restrict__ out) {
  int token = (blockIdx.x * 256 + threadIdx.x) >> 6;
  int lane = threadIdx.x & 63;
  const float* row = in + (size_t)token * CC;
  float4 v0 = *(const float4*)(row + lane * 8);
  float4 v1 = *(const float4*)(row + lane * 8 + 4);
  float s = v0.x + v0.y + v0.z + v0.w + v1.x + v1.y + v1.z + v1.w;
  float ss = v0.x*v0.x + v0.y*v0.y + v0.z*v0.z + v0.w*v0.w
           + v1.x*v1.x + v1.y*v1.y + v1.z*v1.z + v1.w*v1.w;
  #pragma unroll
  for (int o = 32; o; o >>= 1) { s += __shfl_xor(s, o, 64); ss += __shfl_xor(ss, o, 64); }
  float mu = s * (1.f / CC);
  float var = ss * (1.f / CC) - mu * mu;
  float rs = rsqrtf(var + 1e-5f);
  float4 g0 = *(const float4*)(&g[lane * 8]);
  float4 g1 = *(const float4*)(&g[lane * 8 + 4]);
  float4 b0 = *(const float4*)(&b[lane * 8]);
  float4 b1 = *(const float4*)(&b[lane * 8 + 4]);
  unsigned short o8[8];
  o8[0] = f2bf((v0.x - mu) * rs * g0.x + b0.x);
  o8[1] = f2bf((v0.y - mu) * rs * g0.y + b0.y);
  o8[2] = f2bf((v0.z - mu) * rs * g0.z + b0.z);
  o8[3] = f2bf((v0.w - mu) * rs * g0.w + b0.w);
  o8[4] = f2bf((v1.x - mu) * rs * g1.x + b1.x);
  o8[5] = f2bf((v1.y - mu) * rs * g1.y + b1.y);
  o8[6] = f2bf((v1.z - mu) * rs * g1.z + b1.z);
  o8[7] = f2bf((v1.w - mu) * rs * g1.w + b1.w);
  uint4 pk;
  pk.x = (uint32_t)o8[0] | ((uint32_t)o8[1] << 16);
  pk.y = (uint32_t)o8[2] | ((uint32_t)o8[3] << 16);
  pk.z = (uint32_t)o8[4] | ((uint32_t)o8[5] << 16);
  pk.w = (uint32_t)o8[6] | ((uint32_t)o8[7] << 16);
  *(uint4*)(&out[(size_t)token * CC + lane * 8]) = pk;
}

// ---- bf16 MFMA GEMM: 3-buf, 2-ahead prefetch, counted vmcnt, T2 chunk-swizzle ----
// K-loop identical to round-5 (proven). NEW: LDS-restaged vectorized epilogue.
// MODE 0: out bf16 = C + bias; MODE 1: out f32 = C+bias+res; MODE 2: bf16 gelu
#define BM 256
#define BN 128
#define BK 32

template <int MODE>
__global__ __launch_bounds__(512) void gemm_kernel(
    const unsigned short* __restrict__ A, const unsigned short* __restrict__ BT,
    const float* __restrict__ bias, const float* __restrict__ res,
    float* __restrict__ outF, unsigned short* __restrict__ outB,
    int M, int N, int K) {
  __shared__ unsigned short As[3][BM * BK];   // 3 x 16KB
  __shared__ unsigned short Bs[3][BN * BK];   // 3 x 8KB
  // XCD-aware swizzle (all grids divisible by 8)
  int nwg = gridDim.x * gridDim.y;
  int flat = blockIdx.y * gridDim.x + blockIdx.x;
  int swz = (flat & 7) * (nwg >> 3) + (flat >> 3);
  int bx = swz % gridDim.x, by = swz / gridDim.x;
  const int bm = by * BM, bn = bx * BN;
  const int t = threadIdx.x;
  const int wid = t >> 6, lane = t & 63;
  const int wr = wid >> 1, wc = wid & 1;        // 4x2 wave grid
  const int lr = lane & 15;
  // T2 read-side swizzle: chunk = (lane>>4) ^ ((lr>>1)&3); lk in elems
  const int lk = (((lane >> 4) ^ ((lane >> 1) & 3)) & 3) * 8;
  // staging: thread t covers row t>>2, global 16B chunk (t&3)^((row>>1)&3)
  const int srow = t >> 2;
  const int scol = (((t & 3) ^ ((t >> 3) & 3)) & 3) * 8;
  const size_t arow0 = (size_t)(bm + srow) * K + scol;          // A rows 0-127
  const size_t arow1 = (size_t)(bm + 128 + srow) * K + scol;    // A rows 128-255
  const size_t brow  = (size_t)(bn + srow) * K + scol;          // B rows 0-127
  const int ldsA0 = wid * 512;          // wave-uniform LDS dests (elems)
  const int ldsA1 = 4096 + wid * 512;
  const int ldsB  = wid * 512;

  f32x4 acc[4][4] = {};
  const int nt = K / BK;

  // prologue: stage tiles 0 and 1 (3 loads per thread each)
  gload16(&A[arow0],       &As[0][ldsA0]);
  gload16(&A[arow1],       &As[0][ldsA1]);
  gload16(&BT[brow],       &Bs[0][ldsB]);
  gload16(&A[arow0 + BK],  &As[1][ldsA0]);
  gload16(&A[arow1 + BK],  &As[1][ldsA1]);
  gload16(&BT[brow + BK],  &Bs[1][ldsB]);

  for (int tile = 0; tile < nt - 1; ++tile) {
    // wait for tile's 3 loads (allow tile+1's 3 to stay in flight), then sync.
    asm volatile("s_waitcnt vmcnt(3)" ::: "memory");
    __builtin_amdgcn_s_barrier();
    __builtin_amdgcn_sched_barrier(0);
    const unsigned short* as = As[tile % 3];
    const unsigned short* bs = Bs[tile % 3];
    bf16x8 af[4], bfr[4];
    #pragma unroll
    for (int i = 0; i < 4; i++)
      af[i] = *(const bf16x8*)(&as[(wr * 64 + i * 16 + lr) * BK + lk]);
    #pragma unroll
    for (int j = 0; j < 4; j++)
      bfr[j] = *(const bf16x8*)(&bs[(wc * 64 + j * 16 + lr) * BK + lk]);
    // issue prefetch of tile+2 (overwrites buf[(tile-1)%3]; safe after barrier)
    if (tile + 2 < nt) {
      int kt = (tile + 2) * BK;
      int nb = (tile + 2) % 3;
      gload16(&A[arow0 + kt], &As[nb][ldsA0]);
      gload16(&A[arow1 + kt], &As[nb][ldsA1]);
      gload16(&BT[brow + kt], &Bs[nb][ldsB]);
    }
    __builtin_amdgcn_s_setprio(1);
    #pragma unroll
    for (int i = 0; i < 4; i++)
      #pragma unroll
      for (int j = 0; j < 4; j++)
        acc[i][j] = __builtin_amdgcn_mfma_f32_16x16x32_bf16(af[i], bfr[j], acc[i][j], 0, 0, 0);
    __builtin_amdgcn_s_setprio(0);
  }
  // final tile: drain everything
  {
    asm volatile("s_waitcnt vmcnt(0)" ::: "memory");
    __builtin_amdgcn_s_barrier();
    __builtin_amdgcn_sched_barrier(0);
    const unsigned short* as = As[(nt - 1) % 3];
    const unsigned short* bs = Bs[(nt - 1) % 3];
    bf16x8 af[4], bfr[4];
    #pragma unroll
    for (int i = 0; i < 4; i++)
      af[i] = *(const bf16x8*)(&as[(wr * 64 + i * 16 + lr) * BK + lk]);
    #pragma unroll
    for (int j = 0; j < 4; j++)
      bfr[j] = *(const bf16x8*)(&bs[(wc * 64 + j * 16 + lr) * BK + lk]);
    #pragma unroll
    for (int i = 0; i < 4; i++)
      #pragma unroll
      for (int j = 0; j < 4; j++)
        acc[i][j] = __builtin_amdgcn_mfma_f32_16x16x32_bf16(af[i], bfr[j], acc[i][j], 0, 0, 0);
  }

  // ---- epilogue: restage acc via LDS -> coalesced vector stores ----
  // pass i: 64 rows (4 wr-stripes of 16) x 128 cols f32, stride 132 (bank pad)
  {
    float* eps = (float*)&As[0][0];           // 64*132*4 = 33.8 KB < 48 KB (As)
    const int erow = t >> 3;                  // 0..63
    const int ecol0 = (t & 7) * 16;           // 0..112
    const int wrow = wr * 16 + (lane >> 4) * 4;   // + r
    const int wcol = wc * 64 + lr;                // + j*16
    const int gr_base = bm + (erow >> 4) * 64 + (erow & 15);
    const int gc0 = bn + ecol0;
    float bv[16];
    #pragma unroll
    for (int c4 = 0; c4 < 4; c4++)
      *(float4*)&bv[c4 * 4] = *(const float4*)&bias[gc0 + c4 * 4];
    #pragma unroll
    for (int i = 0; i < 4; i++) {
      __syncthreads();
      #pragma unroll
      for (int j = 0; j < 4; j++)
        #pragma unroll
        for (int r = 0; r < 4; r++)
          eps[(wrow + r) * 132 + wcol + j * 16] = acc[i][j][r];
      __syncthreads();
      float vv[16];
      #pragma unroll
      for (int c4 = 0; c4 < 4; c4++)
        *(float4*)&vv[c4 * 4] = *(const float4*)&eps[erow * 132 + ecol0 + c4 * 4];
      const size_t off = (size_t)(gr_base + i * 16) * N + gc0;
      if (MODE == 1) {
        #pragma unroll
        for (int c4 = 0; c4 < 4; c4++) {
          float4 rv = *(const float4*)&res[off + c4 * 4];
          float4 ov;
          ov.x = vv[c4*4+0] + bv[c4*4+0] + rv.x;
          ov.y = vv[c4*4+1] + bv[c4*4+1] + rv.y;
          ov.z = vv[c4*4+2] + bv[c4*4+2] + rv.z;
          ov.w = vv[c4*4+3] + bv[c4*4+3] + rv.w;
          *(float4*)&outF[off + c4 * 4] = ov;
        }
      } else {
        unsigned short ob[16];
        #pragma unroll
        for (int c = 0; c < 16; c++) {
          float v = vv[c] + bv[c];
          if (MODE == 2) {
            // gelu(v) = v * sigmoid(2u), u = 0.79788456(v + 0.044715 v^3)
            float a2 = v * v;
            float w = v * fmaf(a2, -0.1029436f, -2.3024849f);   // -2*log2e*u
            float sg = __builtin_amdgcn_rcpf(1.f + __builtin_amdgcn_exp2f(w));
            v = v * sg;
          }
          ob[c] = f2bf(v);
        }
        *(uint4*)&outB[off]     = *(uint4*)&ob[0];
        *(uint4*)&outB[off + 8] = *(uint4*)&ob[8];
      }
    }
  }
}

// ---------------- MFMA window attention: 1 wave per (window, head) ----------------
#define WNS 68   // LDS row stride (elems): 136B = 8B aligned, odd-dword for banks

__global__ __launch_bounds__(64) void attn_mfma_kernel(
    const unsigned short* __restrict__ qkv, unsigned short* __restrict__ out) {
  __shared__ unsigned short VT[64 * WNS];   // V^T: [d][k]
  __shared__ unsigned short Ps[64 * WNS];   // P:   [q][k]
  const int task = blockIdx.x;
  const int win = task >> 3, h = task & 7;
  const int b = win >> 8, wy = (win >> 4) & 15, wx = win & 15;
  const int lane = threadIdx.x;
  const int lr = lane & 15, g = lane >> 4;

  auto tokof = [&](int r) {
    int rr = r > 48 ? 48 : r;
    int y = rr / 7, x2 = rr - y * 7;
    return (size_t)(b * LLEN + (wy * 7 + y) * WW + wx * 7 + x2);
  };

  // ---- stage V^T (scalar writes: per-instruction row base uniform -> conflict-free)
  {
    size_t vbase = tokof(lane) * 1536 + h * 64 + 1024;
    bool valid = lane <= 48;
    #pragma unroll
    for (int c = 0; c < 8; c++) {
      uint4 v = *(const uint4*)(&qkv[vbase + c * 8]);
      const unsigned short* pv = (const unsigned short*)&v;
      #pragma unroll
      for (int e = 0; e < 8; e++)
        VT[(c * 8 + e) * WNS + lane] = valid ? pv[e] : (unsigned short)0;
    }
  }

  // ---- Q,K fragments straight from global (A/B frag rows = lr + 16*tile)
  size_t tok[4];
  #pragma unroll
  for (int i2 = 0; i2 < 4; i2++) tok[i2] = tokof(i2 * 16 + lr);
  bf16x8 Qf[4][2], Kf[4][2];
  #pragma unroll
  for (int i2 = 0; i2 < 4; i2++) {
    size_t base = tok[i2] * 1536 + h * 64 + g * 8;
    #pragma unroll
    for (int ks = 0; ks < 2; ks++) {
      Qf[i2][ks] = *(const bf16x8*)(&qkv[base + ks * 32]);
      Kf[i2][ks] = *(const bf16x8*)(&qkv[base + 512 + ks * 32]);
    }
  }

  // ---- S^T = K·Q^T : acc[i=k-tile][j=q-tile], C row = k, col = q
  f32x4 acc[4][4] = {};
  #pragma unroll
  for (int ks = 0; ks < 2; ks++)
    #pragma unroll
    for (int i2 = 0; i2 < 4; i2++)
      #pragma unroll
      for (int j = 0; j < 4; j++)
        acc[i2][j] = __builtin_amdgcn_mfma_f32_16x16x32_bf16(Kf[i2][ks], Qf[j][ks], acc[i2][j], 0, 0, 0);

  // ---- softmax over k (row axis of S^T): in-reg over 16 vals + shfl 16,32
  #pragma unroll
  for (int j = 0; j < 4; j++) {
    float mx = -1e30f;
    #pragma unroll
    for (int i2 = 0; i2 < 4; i2++)
      #pragma unroll
      for (int r = 0; r < 4; r++) {
        int k = 16 * i2 + 4 * g + r;
        mx = fmaxf(mx, (k <= 48) ? acc[i2][j][r] : -1e30f);
      }
    mx = fmaxf(mx, __shfl_xor(mx, 16, 64));
    mx = fmaxf(mx, __shfl_xor(mx, 32, 64));
    float p[4][4];
    float sum = 0.f;
    #pragma unroll
    for (int i2 = 0; i2 < 4; i2++)
      #pragma unroll
      for (int r = 0; r < 4; r++) {
        int k = 16 * i2 + 4 * g + r;
        float e = (k <= 48) ? __expf(0.125f * (acc[i2][j][r] - mx)) : 0.f;
        p[i2][r] = e; sum += e;
      }
    sum += __shfl_xor(sum, 16, 64);
    sum += __shfl_xor(sum, 32, 64);
    float inv = 1.f / sum;
    int q = 16 * j + lr;
    #pragma unroll
    for (int i2 = 0; i2 < 4; i2++) {
      uint2 w;
      w.x = (uint32_t)f2bf(p[i2][0] * inv) | ((uint32_t)f2bf(p[i2][1] * inv) << 16);
      w.y = (uint32_t)f2bf(p[i2][2] * inv) | ((uint32_t)f2bf(p[i2][3] * inv) << 16);
      *(uint2*)(&Ps[q * WNS + 16 * i2 + 4 * g]) = w;
    }
  }

  __syncthreads();   // VT + Ps writes -> reads fence

  // ---- O = P·V : A = P[q][k], B^T = VT[d][k]; o[i=q-tile][j=d-tile]
  f32x4 o[4][4] = {};
  #pragma unroll
  for (int ks = 0; ks < 2; ks++) {
    bf16x8 Pf[4], Vf[4];
    #pragma unroll
    for (int i2 = 0; i2 < 4; i2++) {
      int base = (16 * i2 + lr) * WNS + ks * 32 + g * 8;
      uint2 lo = *(const uint2*)(&Ps[base]);
      uint2 hi = *(const uint2*)(&Ps[base + 4]);
      uint4 u; u.x = lo.x; u.y = lo.y; u.z = hi.x; u.w = hi.y;
      Pf[i2] = *(bf16x8*)&u;
    }
    #pragma unroll
    for (int j = 0; j < 4; j++) {
      int base = (16 * j + lr) * WNS + ks * 32 + g * 8;
      uint2 lo = *(const uint2*)(&VT[base]);
      uint2 hi = *(const uint2*)(&VT[base + 4]);
      uint4 u; u.x = lo.x; u.y = lo.y; u.z = hi.x; u.w = hi.y;
      Vf[j] = *(bf16x8*)&u;
    }
    #pragma unroll
    for (int i2 = 0; i2 < 4; i2++)
      #pragma unroll
      for (int j = 0; j < 4; j++)
        o[i2][j] = __builtin_amdgcn_mfma_f32_16x16x32_bf16(Pf[i2], Vf[j], o[i2][j], 0, 0, 0);
  }

  // ---- store O rows q<49
  #pragma unroll
  for (int i2 = 0; i2 < 4; i2++)
    #pragma unroll
    for (int r = 0; r < 4; r++) {
      int q = 16 * i2 + 4 * g + r;
      if (q <= 48) {
        size_t obase = tokof(q) * 512 + h * 64 + lr;
        #pragma unroll
        for (int j = 0; j < 4; j++)
          out[obase + 16 * j] = f2bf(o[i2][j][r]);
      }
    }
}

extern "C" void kernel_launch(void* const* d_in, const int* in_sizes, int n_in,
                              void* d_out, int out_size, void* d_ws, size_t ws_size,
                              hipStream_t stream) {
  const float* x      = (const float*)d_in[0];
  const float* cpe0_w = (const float*)d_in[1];
  const float* cpe0_b = (const float*)d_in[2];
  const float* cpe1_w = (const float*)d_in[3];
  const float* cpe1_b = (const float*)d_in[4];
  const float* ln1_g  = (const float*)d_in[5];
  const float* ln1_b  = (const float*)d_in[6];
  const float* ln2_g  = (const float*)d_in[7];
  const float* ln2_b  = (const float*)d_in[8];
  const float* qkv_w  = (const float*)d_in[9];
  const float* qkv_b  = (const float*)d_in[10];
  const float* proj_w = (const float*)d_in[11];
  const float* proj_b = (const float*)d_in[12];
  const float* fc1_w  = (const float*)d_in[13];
  const float* fc1_b  = (const float*)d_in[14];
  const float* fc2_w  = (const float*)d_in[15];
  const float* fc2_b  = (const float*)d_in[16];
  float* out = (float*)d_out;
  char* ws = (char*)d_ws;

  unsigned short* qkvwT  = (unsigned short*)(ws + 0);           // 1536x512 bf16
  unsigned short* projwT = (unsigned short*)(ws + 1572864);     // 512x512
  unsigned short* fc1wT  = (unsigned short*)(ws + 2097152);     // 2048x512
  unsigned short* fc2wT  = (unsigned short*)(ws + 4194304);     // 512x2048
  float*          shortc = (float*)(ws + 6291456);              // 50176x512 f32
  unsigned short* lnb    = (unsigned short*)(ws + 109051904);   // 50176x512 bf16
  unsigned short* qkvb   = (unsigned short*)(ws + 160432128);   // 50176x1536 bf16
  unsigned short* attnb  = (unsigned short*)(ws + 314572800);   // 50176x512 bf16
  unsigned short* gelub  = qkvb;   // overlay: 50176x2048 bf16
  float* h2 = out;                 // reuse d_out as h2 scratch

  wtranspose_kernel<<<(512 * 1536 + 255) / 256, 256, 0, stream>>>(qkv_w, qkvwT, 512, 1536);
  wtranspose_kernel<<<(512 * 512 + 255) / 256, 256, 0, stream>>>(proj_w, projwT, 512, 512);
  wtranspose_kernel<<<(512 * 2048 + 255) / 256, 256, 0, stream>>>(fc1_w, fc1wT, 512, 2048);
  wtranspose_kernel<<<(2048 * 512 + 255) / 256, 256, 0, stream>>>(fc2_w, fc2wT, 2048, 512);

  const int pixblocks = (BB * HH * WW * 128) / 256;   // 25088
  cpe_kernel<<<pixblocks, 256, 0, stream>>>(x, cpe0_w, cpe0_b, shortc);
  ln_kernel<<<NTOK / 4, 256, 0, stream>>>(shortc, ln1_g, ln1_b, lnb);
  gemm_kernel<0><<<dim3(12, 196), 512, 0, stream>>>(lnb, qkvwT, qkv_b, nullptr,
                                                    nullptr, qkvb, NTOK, 1536, 512);
  attn_mfma_kernel<<<8192, 64, 0, stream>>>(qkvb, attnb);
  gemm_kernel<1><<<dim3(4, 196), 512, 0, stream>>>(attnb, projwT, proj_b, shortc,
                                                   shortc, nullptr, NTOK, 512, 512);
  cpe_kernel<<<pixblocks, 256, 0, stream>>>(shortc, cpe1_w, cpe1_b, h2);
  ln_kernel<<<NTOK / 4, 256, 0, stream>>>(h2, ln2_g, ln2_b, lnb);
  gemm_kernel<2><<<dim3(16, 196), 512, 0, stream>>>(lnb, fc1wT, fc1_b, nullptr,
                                                    nullptr, gelub, NTOK, 2048, 512);
  gemm_kernel<1><<<dim3(4, 196), 512, 0, stream>>>(gelub, fc2wT, fc2_b, h2,
                                                   out, nullptr, NTOK, 512, 2048);
}

// Round 8
// 695.548 us; speedup vs baseline: 1.2158x; 1.1379x over previous
//
#include <hip/hip_runtime.h>
#include <stdint.h>

#define HH 112
#define WW 112
#define CC 512
#define BB 4
#define LLEN (HH*WW)
#define NTOK (BB*LLEN)   // 50176
#define NHEADS 8
#define HD 64
#define HIDDEN 2048

typedef __bf16 bf16x8 __attribute__((ext_vector_type(8)));
typedef float f32x4 __attribute__((ext_vector_type(4)));
typedef long i64;

__device__ __forceinline__ unsigned short f2bf(float x) {
  uint32_t u = __float_as_uint(x);
  u += 0x7fffu + ((u >> 16) & 1u);
  return (unsigned short)(u >> 16);
}
__device__ __forceinline__ float bf2f(unsigned short h) {
  return __uint_as_float((uint32_t)h << 16);
}
// pack 4 f32 -> 4 fp8 e4m3 (OCP on gfx950) in one int
__device__ __forceinline__ int cvt4_fp8(float a, float b, float c, float d) {
  int r = 0;
  r = __builtin_amdgcn_cvt_pk_fp8_f32(a, b, r, false);
  r = __builtin_amdgcn_cvt_pk_fp8_f32(c, d, r, true);
  return r;
}

// async global->LDS, 16B per lane; lds dest must be wave-uniform base
__device__ __forceinline__ void gload16(const void* gptr, void* lptr) {
  __builtin_amdgcn_global_load_lds(
      (const __attribute__((address_space(1))) void*)gptr,
      (__attribute__((address_space(3))) void*)lptr,
      16, 0, 0);
}

// ---------------- weight transpose (K,N) f32 -> (N,K) bf16 ----------------
__global__ __launch_bounds__(256) void wtranspose_kernel(
    const float* __restrict__ w, unsigned short* __restrict__ wt, int K, int N) {
  int idx = blockIdx.x * 256 + threadIdx.x;
  if (idx >= K * N) return;
  int k = idx / N, n = idx - k * N;
  wt[(size_t)n * K + k] = f2bf(w[idx]);
}

// ---------------- weight transpose (K,N) f32 -> (N,K) fp8, scaled x32 --------
__global__ __launch_bounds__(256) void wtranspose8_kernel(
    const float* __restrict__ w, unsigned char* __restrict__ wt, int K, int N) {
  int idx = blockIdx.x * 256 + threadIdx.x;   // index over OUTPUT (coalesced)
  if (idx >= K * N) return;
  int n = idx / K, k = idx - n * K;
  float v = w[(size_t)k * N + n] * 32.f;
  int r = __builtin_amdgcn_cvt_pk_fp8_f32(v, v, 0, false);
  wt[idx] = (unsigned char)r;
}

// ---------------- depthwise 3x3 conv + bias + residual ----------------
__global__ __launch_bounds__(256) void cpe_kernel(
    const float* __restrict__ x, const float* __restrict__ w,
    const float* __restrict__ bias, float* __restrict__ out) {
  int tid = blockIdx.x * 256 + threadIdx.x;
  int c = (tid & 127) << 2;      // channel chunk of 4
  int pix = tid >> 7;
  int xx = pix % WW; int t2 = pix / WW; int yy = t2 % HH; int bb = t2 / HH;
  float4 bv = *(const float4*)(&bias[c]);
  float ax = bv.x, ay = bv.y, az = bv.z, aw = bv.w;
  #pragma unroll
  for (int ky = 0; ky < 3; ky++) {
    int y = yy + ky - 1;
    if ((unsigned)y >= (unsigned)HH) continue;
    #pragma unroll
    for (int kx = 0; kx < 3; kx++) {
      int x2 = xx + kx - 1;
      if ((unsigned)x2 >= (unsigned)WW) continue;
      const float4 v = *(const float4*)(&x[(((size_t)bb * HH + y) * WW + x2) * CC + c]);
      const float4 wv = *(const float4*)(&w[(ky * 3 + kx) * CC + c]);
      ax = fmaf(v.x, wv.x, ax); ay = fmaf(v.y, wv.y, ay);
      az = fmaf(v.z, wv.z, az); aw = fmaf(v.w, wv.w, aw);
    }
  }
  size_t o = (size_t)pix * CC + c;
  const float4 xv = *(const float4*)(&x[o]);
  float4 r; r.x = xv.x + ax; r.y = xv.y + ay; r.z = xv.z + az; r.w = xv.w + aw;
  *(float4*)(&out[o]) = r;
}

// ---------------- LayerNorm (C=512), one wave per token ----------------
// OUT8=0: bf16 out ; OUT8=1: fp8 e4m3 out
template <int OUT8>
__global__ __launch_bounds__(256) void ln_kernel(
    const float* __restrict__ in, const float* __restrict__ g,
    const float* __restrict__ b, unsigned short* __restrict__ out,
    unsigned char* __restrict__ out8) {
  int token = (blockIdx.x * 256 + threadIdx.x) >> 6;
  int lane = threadIdx.x & 63;
  const float* row = in + (size_t)token * CC;
  float4 v0 = *(const float4*)(row + lane * 8);
  float4 v1 = *(const float4*)(row + lane * 8 + 4);
  float s = v0.x + v0.y + v0.z + v0.w + v1.x + v1.y + v1.z + v1.w;
  float ss = v0.x*v0.x + v0.y*v0.y + v0.z*v0.z + v0.w*v0.w
           + v1.x*v1.x + v1.y*v1.y + v1.z*v1.z + v1.w*v1.w;
  #pragma unroll
  for (int o = 32; o; o >>= 1) { s += __shfl_xor(s, o, 64); ss += __shfl_xor(ss, o, 64); }
  float mu = s * (1.f / CC);
  float var = ss * (1.f / CC) - mu * mu;
  float rs = rsqrtf(var + 1e-5f);
  float4 g0 = *(const float4*)(&g[lane * 8]);
  float4 g1 = *(const float4*)(&g[lane * 8 + 4]);
  float4 b0 = *(const float4*)(&b[lane * 8]);
  float4 b1 = *(const float4*)(&b[lane * 8 + 4]);
  float o8[8];
  o8[0] = (v0.x - mu) * rs * g0.x + b0.x;
  o8[1] = (v0.y - mu) * rs * g0.y + b0.y;
  o8[2] = (v0.z - mu) * rs * g0.z + b0.z;
  o8[3] = (v0.w - mu) * rs * g0.w + b0.w;
  o8[4] = (v1.x - mu) * rs * g1.x + b1.x;
  o8[5] = (v1.y - mu) * rs * g1.y + b1.y;
  o8[6] = (v1.z - mu) * rs * g1.z + b1.z;
  o8[7] = (v1.w - mu) * rs * g1.w + b1.w;
  if (OUT8) {
    uint2 pk;
    pk.x = (uint32_t)cvt4_fp8(o8[0], o8[1], o8[2], o8[3]);
    pk.y = (uint32_t)cvt4_fp8(o8[4], o8[5], o8[6], o8[7]);
    *(uint2*)(&out8[(size_t)token * CC + lane * 8]) = pk;
  } else {
    uint4 pk;
    pk.x = (uint32_t)f2bf(o8[0]) | ((uint32_t)f2bf(o8[1]) << 16);
    pk.y = (uint32_t)f2bf(o8[2]) | ((uint32_t)f2bf(o8[3]) << 16);
    pk.z = (uint32_t)f2bf(o8[4]) | ((uint32_t)f2bf(o8[5]) << 16);
    pk.w = (uint32_t)f2bf(o8[6]) | ((uint32_t)f2bf(o8[7]) << 16);
    *(uint4*)(&out[(size_t)token * CC + lane * 8]) = pk;
  }
}

// ---- bf16 MFMA GEMM: 3-buf, 2-ahead prefetch, counted vmcnt, T2 chunk-swizzle ----
// MODE 0: out bf16 = C + bias; MODE 1: out f32 = C+bias+res; MODE 2: bf16 gelu
#define BM 256
#define BN 128
#define BK 32

template <int MODE>
__global__ __launch_bounds__(512) void gemm_kernel(
    const unsigned short* __restrict__ A, const unsigned short* __restrict__ BT,
    const float* __restrict__ bias, const float* __restrict__ res,
    float* __restrict__ outF, unsigned short* __restrict__ outB,
    int M, int N, int K) {
  __shared__ unsigned short As[3][BM * BK];   // 3 x 16KB
  __shared__ unsigned short Bs[3][BN * BK];   // 3 x 8KB
  int nwg = gridDim.x * gridDim.y;
  int flat = blockIdx.y * gridDim.x + blockIdx.x;
  int swz = (flat & 7) * (nwg >> 3) + (flat >> 3);
  int bx = swz % gridDim.x, by = swz / gridDim.x;
  const int bm = by * BM, bn = bx * BN;
  const int t = threadIdx.x;
  const int wid = t >> 6, lane = t & 63;
  const int wr = wid >> 1, wc = wid & 1;        // 4x2 wave grid
  const int lr = lane & 15;
  const int lk = (((lane >> 4) ^ ((lane >> 1) & 3)) & 3) * 8;
  const int srow = t >> 2;
  const int scol = (((t & 3) ^ ((t >> 3) & 3)) & 3) * 8;
  const size_t arow0 = (size_t)(bm + srow) * K + scol;
  const size_t arow1 = (size_t)(bm + 128 + srow) * K + scol;
  const size_t brow  = (size_t)(bn + srow) * K + scol;
  const int ldsA0 = wid * 512;
  const int ldsA1 = 4096 + wid * 512;
  const int ldsB  = wid * 512;

  f32x4 acc[4][4] = {};
  const int nt = K / BK;

  gload16(&A[arow0],       &As[0][ldsA0]);
  gload16(&A[arow1],       &As[0][ldsA1]);
  gload16(&BT[brow],       &Bs[0][ldsB]);
  gload16(&A[arow0 + BK],  &As[1][ldsA0]);
  gload16(&A[arow1 + BK],  &As[1][ldsA1]);
  gload16(&BT[brow + BK],  &Bs[1][ldsB]);

  for (int tile = 0; tile < nt - 1; ++tile) {
    asm volatile("s_waitcnt vmcnt(3)" ::: "memory");
    __builtin_amdgcn_s_barrier();
    __builtin_amdgcn_sched_barrier(0);
    const unsigned short* as = As[tile % 3];
    const unsigned short* bs = Bs[tile % 3];
    bf16x8 af[4], bfr[4];
    #pragma unroll
    for (int i = 0; i < 4; i++)
      af[i] = *(const bf16x8*)(&as[(wr * 64 + i * 16 + lr) * BK + lk]);
    #pragma unroll
    for (int j = 0; j < 4; j++)
      bfr[j] = *(const bf16x8*)(&bs[(wc * 64 + j * 16 + lr) * BK + lk]);
    if (tile + 2 < nt) {
      int kt = (tile + 2) * BK;
      int nb = (tile + 2) % 3;
      gload16(&A[arow0 + kt], &As[nb][ldsA0]);
      gload16(&A[arow1 + kt], &As[nb][ldsA1]);
      gload16(&BT[brow + kt], &Bs[nb][ldsB]);
    }
    __builtin_amdgcn_s_setprio(1);
    #pragma unroll
    for (int i = 0; i < 4; i++)
      #pragma unroll
      for (int j = 0; j < 4; j++)
        acc[i][j] = __builtin_amdgcn_mfma_f32_16x16x32_bf16(af[i], bfr[j], acc[i][j], 0, 0, 0);
    __builtin_amdgcn_s_setprio(0);
  }
  {
    asm volatile("s_waitcnt vmcnt(0)" ::: "memory");
    __builtin_amdgcn_s_barrier();
    __builtin_amdgcn_sched_barrier(0);
    const unsigned short* as = As[(nt - 1) % 3];
    const unsigned short* bs = Bs[(nt - 1) % 3];
    bf16x8 af[4], bfr[4];
    #pragma unroll
    for (int i = 0; i < 4; i++)
      af[i] = *(const bf16x8*)(&as[(wr * 64 + i * 16 + lr) * BK + lk]);
    #pragma unroll
    for (int j = 0; j < 4; j++)
      bfr[j] = *(const bf16x8*)(&bs[(wc * 64 + j * 16 + lr) * BK + lk]);
    #pragma unroll
    for (int i = 0; i < 4; i++)
      #pragma unroll
      for (int j = 0; j < 4; j++)
        acc[i][j] = __builtin_amdgcn_mfma_f32_16x16x32_bf16(af[i], bfr[j], acc[i][j], 0, 0, 0);
  }

  // ---- epilogue: restage acc via LDS -> coalesced vector stores ----
  {
    float* eps = (float*)&As[0][0];
    const int erow = t >> 3;
    const int ecol0 = (t & 7) * 16;
    const int wrow = wr * 16 + (lane >> 4) * 4;
    const int wcol = wc * 64 + lr;
    const int gr_base = bm + (erow >> 4) * 64 + (erow & 15);
    const int gc0 = bn + ecol0;
    float bv[16];
    #pragma unroll
    for (int c4 = 0; c4 < 4; c4++)
      *(float4*)&bv[c4 * 4] = *(const float4*)&bias[gc0 + c4 * 4];
    #pragma unroll
    for (int i = 0; i < 4; i++) {
      __syncthreads();
      #pragma unroll
      for (int j = 0; j < 4; j++)
        #pragma unroll
        for (int r = 0; r < 4; r++)
          eps[(wrow + r) * 132 + wcol + j * 16] = acc[i][j][r];
      __syncthreads();
      float vv[16];
      #pragma unroll
      for (int c4 = 0; c4 < 4; c4++)
        *(float4*)&vv[c4 * 4] = *(const float4*)&eps[erow * 132 + ecol0 + c4 * 4];
      const size_t off = (size_t)(gr_base + i * 16) * N + gc0;
      if (MODE == 1) {
        #pragma unroll
        for (int c4 = 0; c4 < 4; c4++) {
          float4 rv = *(const float4*)&res[off + c4 * 4];
          float4 ov;
          ov.x = vv[c4*4+0] + bv[c4*4+0] + rv.x;
          ov.y = vv[c4*4+1] + bv[c4*4+1] + rv.y;
          ov.z = vv[c4*4+2] + bv[c4*4+2] + rv.z;
          ov.w = vv[c4*4+3] + bv[c4*4+3] + rv.w;
          *(float4*)&outF[off + c4 * 4] = ov;
        }
      } else {
        unsigned short ob[16];
        #pragma unroll
        for (int c = 0; c < 16; c++) {
          float v = vv[c] + bv[c];
          if (MODE == 2) {
            float a2 = v * v;
            float w = v * fmaf(a2, -0.1029436f, -2.3024849f);
            float sg = __builtin_amdgcn_rcpf(1.f + __builtin_amdgcn_exp2f(w));
            v = v * sg;
          }
          ob[c] = f2bf(v);
        }
        *(uint4*)&outB[off]     = *(uint4*)&ob[0];
        *(uint4*)&outB[off + 8] = *(uint4*)&ob[8];
      }
    }
  }
}

// ==== fp8 e4m3 MFMA GEMM (MLP): same 3-buf/2-ahead/vmcnt(3) ledger, BK=64 ====
// B pre-scaled x32 -> acc * (1/32) in epilogue.
// MODE 2: out fp8 = gelu(C*s + bias)   (fc1)
// MODE 1: out f32 = C*s + bias + res   (fc2)
#define BK8 64

template <int MODE>
__global__ __launch_bounds__(512) void gemm8_kernel(
    const unsigned char* __restrict__ A, const unsigned char* __restrict__ BT,
    const float* __restrict__ bias, const float* __restrict__ res,
    float* __restrict__ outF, unsigned char* __restrict__ outB8,
    int M, int N, int K) {
  __shared__ unsigned char As[3][BM * BK8];   // 3 x 16KB
  __shared__ unsigned char Bs[3][BN * BK8];   // 3 x 8KB
  int nwg = gridDim.x * gridDim.y;
  int flat = blockIdx.y * gridDim.x + blockIdx.x;
  int swz = (flat & 7) * (nwg >> 3) + (flat >> 3);
  int bx = swz % gridDim.x, by = swz / gridDim.x;
  const int bm = by * BM, bn = bx * BN;
  const int t = threadIdx.x;
  const int wid = t >> 6, lane = t & 63;
  const int wr = wid >> 1, wc = wid & 1;
  const int lr = lane & 15, g = lane >> 4;
  // read swizzle: 16B chunk c(ks) = (ks*2 + (g>>1)) ^ ((lr>>1)&3); byte +=(g&1)*8
  const int swr = (lr >> 1) & 3;
  const int rb0 = (((g >> 1)      ) ^ swr) * 16 + (g & 1) * 8;   // ks=0
  const int rb1 = (((g >> 1) + 2) ^ swr) * 16 + (g & 1) * 8;     // ks=1
  // staging: row t>>2, source 16B chunk (t&3) ^ ((row>>1)&3)  [(t>>3)&3]
  const int srow = t >> 2;
  const int scol = (((t & 3) ^ ((t >> 3) & 3)) & 3) * 16;
  const size_t arow0 = (size_t)(bm + srow) * K + scol;          // A rows 0-127
  const size_t arow1 = (size_t)(bm + 128 + srow) * K + scol;    // A rows 128-255
  const size_t brow  = (size_t)(bn + srow) * K + scol;          // B rows 0-127
  const int ldsA0 = wid * 1024;          // bytes
  const int ldsA1 = 8192 + wid * 1024;
  const int ldsB  = wid * 1024;

  f32x4 acc[4][4] = {};
  const int nt = K / BK8;

  gload16(&A[arow0],        &As[0][ldsA0]);
  gload16(&A[arow1],        &As[0][ldsA1]);
  gload16(&BT[brow],        &Bs[0][ldsB]);
  gload16(&A[arow0 + BK8],  &As[1][ldsA0]);
  gload16(&A[arow1 + BK8],  &As[1][ldsA1]);
  gload16(&BT[brow + BK8],  &Bs[1][ldsB]);

  for (int tile = 0; tile < nt - 1; ++tile) {
    asm volatile("s_waitcnt vmcnt(3)" ::: "memory");
    __builtin_amdgcn_s_barrier();
    __builtin_amdgcn_sched_barrier(0);
    const unsigned char* as = As[tile % 3];
    const unsigned char* bs = Bs[tile % 3];
    i64 af0[4], af1[4], bf0[4], bf1[4];
    #pragma unroll
    for (int i = 0; i < 4; i++) {
      const unsigned char* p = &as[(wr * 64 + i * 16 + lr) * BK8];
      af0[i] = *(const i64*)(p + rb0);
      af1[i] = *(const i64*)(p + rb1);
    }
    #pragma unroll
    for (int j = 0; j < 4; j++) {
      const unsigned char* p = &bs[(wc * 64 + j * 16 + lr) * BK8];
      bf0[j] = *(const i64*)(p + rb0);
      bf1[j] = *(const i64*)(p + rb1);
    }
    if (tile + 2 < nt) {
      int kt = (tile + 2) * BK8;
      int nb = (tile + 2) % 3;
      gload16(&A[arow0 + kt], &As[nb][ldsA0]);
      gload16(&A[arow1 + kt], &As[nb][ldsA1]);
      gload16(&BT[brow + kt], &Bs[nb][ldsB]);
    }
    __builtin_amdgcn_s_setprio(1);
    #pragma unroll
    for (int i = 0; i < 4; i++)
      #pragma unroll
      for (int j = 0; j < 4; j++) {
        acc[i][j] = __builtin_amdgcn_mfma_f32_16x16x32_fp8_fp8(af0[i], bf0[j], acc[i][j], 0, 0, 0);
        acc[i][j] = __builtin_amdgcn_mfma_f32_16x16x32_fp8_fp8(af1[i], bf1[j], acc[i][j], 0, 0, 0);
      }
    __builtin_amdgcn_s_setprio(0);
  }
  {
    asm volatile("s_waitcnt vmcnt(0)" ::: "memory");
    __builtin_amdgcn_s_barrier();
    __builtin_amdgcn_sched_barrier(0);
    const unsigned char* as = As[(nt - 1) % 3];
    const unsigned char* bs = Bs[(nt - 1) % 3];
    i64 af0[4], af1[4], bf0[4], bf1[4];
    #pragma unroll
    for (int i = 0; i < 4; i++) {
      const unsigned char* p = &as[(wr * 64 + i * 16 + lr) * BK8];
      af0[i] = *(const i64*)(p + rb0);
      af1[i] = *(const i64*)(p + rb1);
    }
    #pragma unroll
    for (int j = 0; j < 4; j++) {
      const unsigned char* p = &bs[(wc * 64 + j * 16 + lr) * BK8];
      bf0[j] = *(const i64*)(p + rb0);
      bf1[j] = *(const i64*)(p + rb1);
    }
    #pragma unroll
    for (int i = 0; i < 4; i++)
      #pragma unroll
      for (int j = 0; j < 4; j++) {
        acc[i][j] = __builtin_amdgcn_mfma_f32_16x16x32_fp8_fp8(af0[i], bf0[j], acc[i][j], 0, 0, 0);
        acc[i][j] = __builtin_amdgcn_mfma_f32_16x16x32_fp8_fp8(af1[i], bf1[j], acc[i][j], 0, 0, 0);
      }
  }

  // ---- epilogue (restaged, vectorized), acc scaled by 1/32 ----
  {
    const float SC = 0.03125f;
    float* eps = (float*)&As[0][0];           // 33.8KB < 48KB
    const int erow = t >> 3;
    const int ecol0 = (t & 7) * 16;
    const int wrow = wr * 16 + (lane >> 4) * 4;
    const int wcol = wc * 64 + lr;
    const int gr_base = bm + (erow >> 4) * 64 + (erow & 15);
    const int gc0 = bn + ecol0;
    float bv[16];
    #pragma unroll
    for (int c4 = 0; c4 < 4; c4++)
      *(float4*)&bv[c4 * 4] = *(const float4*)&bias[gc0 + c4 * 4];
    #pragma unroll
    for (int i = 0; i < 4; i++) {
      __syncthreads();
      #pragma unroll
      for (int j = 0; j < 4; j++)
        #pragma unroll
        for (int r = 0; r < 4; r++)
          eps[(wrow + r) * 132 + wcol + j * 16] = acc[i][j][r];
      __syncthreads();
      float vv[16];
      #pragma unroll
      for (int c4 = 0; c4 < 4; c4++)
        *(float4*)&vv[c4 * 4] = *(const float4*)&eps[erow * 132 + ecol0 + c4 * 4];
      const size_t off = (size_t)(gr_base + i * 16) * N + gc0;
      if (MODE == 1) {
        #pragma unroll
        for (int c4 = 0; c4 < 4; c4++) {
          float4 rv = *(const float4*)&res[off + c4 * 4];
          float4 ov;
          ov.x = vv[c4*4+0] * SC + bv[c4*4+0] + rv.x;
          ov.y = vv[c4*4+1] * SC + bv[c4*4+1] + rv.y;
          ov.z = vv[c4*4+2] * SC + bv[c4*4+2] + rv.z;
          ov.w = vv[c4*4+3] * SC + bv[c4*4+3] + rv.w;
          *(float4*)&outF[off + c4 * 4] = ov;
        }
      } else {
        float gv[16];
        #pragma unroll
        for (int c = 0; c < 16; c++) {
          float v = vv[c] * SC + bv[c];
          float a2 = v * v;
          float w = v * fmaf(a2, -0.1029436f, -2.3024849f);
          float sg = __builtin_amdgcn_rcpf(1.f + __builtin_amdgcn_exp2f(w));
          gv[c] = v * sg;
        }
        uint4 pk;
        pk.x = (uint32_t)cvt4_fp8(gv[0],  gv[1],  gv[2],  gv[3]);
        pk.y = (uint32_t)cvt4_fp8(gv[4],  gv[5],  gv[6],  gv[7]);
        pk.z = (uint32_t)cvt4_fp8(gv[8],  gv[9],  gv[10], gv[11]);
        pk.w = (uint32_t)cvt4_fp8(gv[12], gv[13], gv[14], gv[15]);
        *(uint4*)&outB8[off] = pk;
      }
    }
  }
}

// ---------------- MFMA window attention: 1 wave per (window, head) ----------------
#define WNS 68

__global__ __launch_bounds__(64) void attn_mfma_kernel(
    const unsigned short* __restrict__ qkv, unsigned short* __restrict__ out) {
  __shared__ unsigned short VT[64 * WNS];   // V^T: [d][k]
  __shared__ unsigned short Ps[64 * WNS];   // P:   [q][k]
  const int task = blockIdx.x;
  const int win = task >> 3, h = task & 7;
  const int b = win >> 8, wy = (win >> 4) & 15, wx = win & 15;
  const int lane = threadIdx.x;
  const int lr = lane & 15, g = lane >> 4;

  auto tokof = [&](int r) {
    int rr = r > 48 ? 48 : r;
    int y = rr / 7, x2 = rr - y * 7;
    return (size_t)(b * LLEN + (wy * 7 + y) * WW + wx * 7 + x2);
  };

  {
    size_t vbase = tokof(lane) * 1536 + h * 64 + 1024;
    bool valid = lane <= 48;
    #pragma unroll
    for (int c = 0; c < 8; c++) {
      uint4 v = *(const uint4*)(&qkv[vbase + c * 8]);
      const unsigned short* pv = (const unsigned short*)&v;
      #pragma unroll
      for (int e = 0; e < 8; e++)
        VT[(c * 8 + e) * WNS + lane] = valid ? pv[e] : (unsigned short)0;
    }
  }

  size_t tok[4];
  #pragma unroll
  for (int i2 = 0; i2 < 4; i2++) tok[i2] = tokof(i2 * 16 + lr);
  bf16x8 Qf[4][2], Kf[4][2];
  #pragma unroll
  for (int i2 = 0; i2 < 4; i2++) {
    size_t base = tok[i2] * 1536 + h * 64 + g * 8;
    #pragma unroll
    for (int ks = 0; ks < 2; ks++) {
      Qf[i2][ks] = *(const bf16x8*)(&qkv[base + ks * 32]);
      Kf[i2][ks] = *(const bf16x8*)(&qkv[base + 512 + ks * 32]);
    }
  }

  f32x4 acc[4][4] = {};
  #pragma unroll
  for (int ks = 0; ks < 2; ks++)
    #pragma unroll
    for (int i2 = 0; i2 < 4; i2++)
      #pragma unroll
      for (int j = 0; j < 4; j++)
        acc[i2][j] = __builtin_amdgcn_mfma_f32_16x16x32_bf16(Kf[i2][ks], Qf[j][ks], acc[i2][j], 0, 0, 0);

  #pragma unroll
  for (int j = 0; j < 4; j++) {
    float mx = -1e30f;
    #pragma unroll
    for (int i2 = 0; i2 < 4; i2++)
      #pragma unroll
      for (int r = 0; r < 4; r++) {
        int k = 16 * i2 + 4 * g + r;
        mx = fmaxf(mx, (k <= 48) ? acc[i2][j][r] : -1e30f);
      }
    mx = fmaxf(mx, __shfl_xor(mx, 16, 64));
    mx = fmaxf(mx, __shfl_xor(mx, 32, 64));
    float p[4][4];
    float sum = 0.f;
    #pragma unroll
    for (int i2 = 0; i2 < 4; i2++)
      #pragma unroll
      for (int r = 0; r < 4; r++) {
        int k = 16 * i2 + 4 * g + r;
        float e = (k <= 48) ? __expf(0.125f * (acc[i2][j][r] - mx)) : 0.f;
        p[i2][r] = e; sum += e;
      }
    sum += __shfl_xor(sum, 16, 64);
    sum += __shfl_xor(sum, 32, 64);
    float inv = 1.f / sum;
    int q = 16 * j + lr;
    #pragma unroll
    for (int i2 = 0; i2 < 4; i2++) {
      uint2 w;
      w.x = (uint32_t)f2bf(p[i2][0] * inv) | ((uint32_t)f2bf(p[i2][1] * inv) << 16);
      w.y = (uint32_t)f2bf(p[i2][2] * inv) | ((uint32_t)f2bf(p[i2][3] * inv) << 16);
      *(uint2*)(&Ps[q * WNS + 16 * i2 + 4 * g]) = w;
    }
  }

  __syncthreads();

  f32x4 o[4][4] = {};
  #pragma unroll
  for (int ks = 0; ks < 2; ks++) {
    bf16x8 Pf[4], Vf[4];
    #pragma unroll
    for (int i2 = 0; i2 < 4; i2++) {
      int base = (16 * i2 + lr) * WNS + ks * 32 + g * 8;
      uint2 lo = *(const uint2*)(&Ps[base]);
      uint2 hi = *(const uint2*)(&Ps[base + 4]);
      uint4 u; u.x = lo.x; u.y = lo.y; u.z = hi.x; u.w = hi.y;
      Pf[i2] = *(bf16x8*)&u;
    }
    #pragma unroll
    for (int j = 0; j < 4; j++) {
      int base = (16 * j + lr) * WNS + ks * 32 + g * 8;
      uint2 lo = *(const uint2*)(&VT[base]);
      uint2 hi = *(const uint2*)(&VT[base + 4]);
      uint4 u; u.x = lo.x; u.y = lo.y; u.z = hi.x; u.w = hi.y;
      Vf[j] = *(bf16x8*)&u;
    }
    #pragma unroll
    for (int i2 = 0; i2 < 4; i2++)
      #pragma unroll
      for (int j = 0; j < 4; j++)
        o[i2][j] = __builtin_amdgcn_mfma_f32_16x16x32_bf16(Pf[i2], Vf[j], o[i2][j], 0, 0, 0);
  }

  #pragma unroll
  for (int i2 = 0; i2 < 4; i2++)
    #pragma unroll
    for (int r = 0; r < 4; r++) {
      int q = 16 * i2 + 4 * g + r;
      if (q <= 48) {
        size_t obase = tokof(q) * 512 + h * 64 + lr;
        #pragma unroll
        for (int j = 0; j < 4; j++)
          out[obase + 16 * j] = f2bf(o[i2][j][r]);
      }
    }
}

extern "C" void kernel_launch(void* const* d_in, const int* in_sizes, int n_in,
                              void* d_out, int out_size, void* d_ws, size_t ws_size,
                              hipStream_t stream) {
  const float* x      = (const float*)d_in[0];
  const float* cpe0_w = (const float*)d_in[1];
  const float* cpe0_b = (const float*)d_in[2];
  const float* cpe1_w = (const float*)d_in[3];
  const float* cpe1_b = (const float*)d_in[4];
  const float* ln1_g  = (const float*)d_in[5];
  const float* ln1_b  = (const float*)d_in[6];
  const float* ln2_g  = (const float*)d_in[7];
  const float* ln2_b  = (const float*)d_in[8];
  const float* qkv_w  = (const float*)d_in[9];
  const float* qkv_b  = (const float*)d_in[10];
  const float* proj_w = (const float*)d_in[11];
  const float* proj_b = (const float*)d_in[12];
  const float* fc1_w  = (const float*)d_in[13];
  const float* fc1_b  = (const float*)d_in[14];
  const float* fc2_w  = (const float*)d_in[15];
  const float* fc2_b  = (const float*)d_in[16];
  float* out = (float*)d_out;
  char* ws = (char*)d_ws;

  unsigned short* qkvwT  = (unsigned short*)(ws + 0);           // 1536x512 bf16
  unsigned short* projwT = (unsigned short*)(ws + 1572864);     // 512x512 bf16
  unsigned char*  fc1wT8 = (unsigned char*)(ws + 2097152);      // 2048x512 fp8 (1MB)
  unsigned char*  fc2wT8 = (unsigned char*)(ws + 4194304);      // 512x2048 fp8 (1MB)
  float*          shortc = (float*)(ws + 6291456);              // 50176x512 f32
  unsigned short* lnb    = (unsigned short*)(ws + 109051904);   // 50176x512 bf16
  unsigned char*  lnb8   = (unsigned char*)(ws + 109051904);    // overlay (ln2 after qkv)
  unsigned short* qkvb   = (unsigned short*)(ws + 160432128);   // 50176x1536 bf16
  unsigned short* attnb  = (unsigned short*)(ws + 314572800);   // 50176x512 bf16
  unsigned char*  gelub8 = (unsigned char*)(ws + 160432128);    // overlay qkvb (fp8 103MB)
  float* h2 = out;                 // reuse d_out as h2 scratch

  wtranspose_kernel<<<(512 * 1536 + 255) / 256, 256, 0, stream>>>(qkv_w, qkvwT, 512, 1536);
  wtranspose_kernel<<<(512 * 512 + 255) / 256, 256, 0, stream>>>(proj_w, projwT, 512, 512);
  wtranspose8_kernel<<<(512 * 2048 + 255) / 256, 256, 0, stream>>>(fc1_w, fc1wT8, 512, 2048);
  wtranspose8_kernel<<<(2048 * 512 + 255) / 256, 256, 0, stream>>>(fc2_w, fc2wT8, 2048, 512);

  const int pixblocks = (BB * HH * WW * 128) / 256;   // 25088
  cpe_kernel<<<pixblocks, 256, 0, stream>>>(x, cpe0_w, cpe0_b, shortc);
  ln_kernel<0><<<NTOK / 4, 256, 0, stream>>>(shortc, ln1_g, ln1_b, lnb, nullptr);
  gemm_kernel<0><<<dim3(12, 196), 512, 0, stream>>>(lnb, qkvwT, qkv_b, nullptr,
                                                    nullptr, qkvb, NTOK, 1536, 512);
  attn_mfma_kernel<<<8192, 64, 0, stream>>>(qkvb, attnb);
  gemm_kernel<1><<<dim3(4, 196), 512, 0, stream>>>(attnb, projwT, proj_b, shortc,
                                                   shortc, nullptr, NTOK, 512, 512);
  cpe_kernel<<<pixblocks, 256, 0, stream>>>(shortc, cpe1_w, cpe1_b, h2);
  ln_kernel<1><<<NTOK / 4, 256, 0, stream>>>(h2, ln2_g, ln2_b, nullptr, lnb8);
  // fc1: fp8 x fp8(x32), gelu -> fp8
  gemm8_kernel<2><<<dim3(16, 196), 512, 0, stream>>>(lnb8, fc1wT8, fc1_b, nullptr,
                                                     nullptr, gelub8, NTOK, 2048, 512);
  // fc2: fp8 x fp8(x32) -> f32 + h2 residual
  gemm8_kernel<1><<<dim3(4, 196), 512, 0, stream>>>(gelub8, fc2wT8, fc2_b, h2,
                                                    out, nullptr, NTOK, 512, 2048);
}